// Round 9
// baseline (857.188 us; speedup 1.0000x reference)
//
#include <hip/hip_runtime.h>
#include <hip/hip_fp16.h>
#include <stdint.h>

// ---------------------------------------------------------------------------
// Seq2SeqARDiffusion on MI355X.
//   k_prep_xh : pack [x_hist|emb] fp16 inputs for LSTM0, layout [t][b][12 u32]
//   k_prep_w  : pack LSTM weights into MFMA A-fragment order (+ W2, bias sums,
//               + tprojG/hprojG/ccG tables in k_diff fragment order)
//   k_lstm0   : persistent MFMA LSTM layer 0, 64 WGs x 512 thr, 16 batch/WG
//   k_lstm1   : persistent MFMA LSTM layer 1 -> enc_out, same structure
//   k_diff    : round-14 DUAL-CHAIN: r13 post-mortem showed the step has a
//               ~850cy FIXED stall (barrier + LDS round-trip + load latency)
//               insensitive to scheduling (r10/r12/r13 all regressed). Fix:
//               each WG advances TWO independent diffusion chains (32
//               batches, groups A/B) per barrier. Compute A and B back to
//               back (independent -> ILP covers MFMA latency), ONE barrier,
//               read both partial sets, update both ys. tproj/cc shared
//               (chains in lockstep). ~+64 VGPR vs r11 (~220, no spill).
//               LSTMs/preps reverted to the r11 form (r13 splits regressed).
// ---------------------------------------------------------------------------

typedef __attribute__((ext_vector_type(2))) _Float16 half2_t;
typedef __attribute__((ext_vector_type(8))) _Float16 v8h;
typedef __attribute__((ext_vector_type(4))) float v4f;

#define DEV __device__ __forceinline__

DEV uint32_t pack2f(float a, float b) {
  __half ha = __float2half_rn(a), hb = __float2half_rn(b);
  return (uint32_t)__half_as_ushort(ha) | ((uint32_t)__half_as_ushort(hb) << 16);
}

DEV float2 up2(uint32_t u) {
  half2_t h = __builtin_bit_cast(half2_t, u);
  return make_float2((float)h.x, (float)h.y);
}

DEV float fast_ex2(float x) {
#if __has_builtin(__builtin_amdgcn_exp2f)
  return __builtin_amdgcn_exp2f(x);
#else
  return exp2f(x);
#endif
}
DEV float fast_rcp(float x) {
#if __has_builtin(__builtin_amdgcn_rcpf)
  return __builtin_amdgcn_rcpf(x);
#else
  return 1.f / x;
#endif
}
DEV float sigm(float x) { return fast_rcp(1.f + fast_ex2(-1.4426950408889634f * x)); }
DEV float tanh_f(float x) {
  return 2.f * fast_rcp(1.f + fast_ex2(-2.8853900817779268f * x)) - 1.f;
}

DEV uint32_t pk_add(uint32_t a, uint32_t b) {
  return __builtin_bit_cast(uint32_t,
      __builtin_bit_cast(half2_t, a) + __builtin_bit_cast(half2_t, b));
}

// relu(w*y + b), packed fp16
DEV uint32_t pk_relufma(uint32_t w, uint32_t y, uint32_t b) {
  half2_t r = __builtin_bit_cast(half2_t, w) * __builtin_bit_cast(half2_t, y) +
              __builtin_bit_cast(half2_t, b);
  half2_t z = {(_Float16)0.f, (_Float16)0.f};
#if __has_builtin(__builtin_elementwise_max)
  r = __builtin_elementwise_max(r, z);
#else
  uint32_t u = __builtin_bit_cast(uint32_t, r);
  uint32_t mask = ((u >> 15) & 1u) * 0xFFFFu | ((u >> 31) & 1u) * 0xFFFF0000u;
  r = __builtin_bit_cast(half2_t, u & ~mask);
#endif
  return __builtin_bit_cast(uint32_t, r);
}

DEV uint32_t pk_max0(uint32_t a) {
  half2_t z = {(_Float16)0.f, (_Float16)0.f};
#if __has_builtin(__builtin_elementwise_max)
  return __builtin_bit_cast(uint32_t,
      __builtin_elementwise_max(__builtin_bit_cast(half2_t, a), z));
#else
  uint32_t mask = ((a >> 15) & 1u) * 0xFFFFu | ((a >> 31) & 1u) * 0xFFFF0000u;
  return a & ~mask;
#endif
}

DEV uint32_t cvtpk(float y) {
#if __has_builtin(__builtin_amdgcn_cvt_pkrtz)
  return __builtin_bit_cast(uint32_t, __builtin_amdgcn_cvt_pkrtz(y, y));
#else
  return pack2f(y, y);
#endif
}

DEV uint32_t cvtpk2(float a, float b) {
#if __has_builtin(__builtin_amdgcn_cvt_pkrtz)
  return __builtin_bit_cast(uint32_t, __builtin_amdgcn_cvt_pkrtz(a, b));
#else
  return pack2f(a, b);
#endif
}

DEV half2_t pk_fma2(uint32_t a, uint32_t b, half2_t c) {
  return __builtin_bit_cast(half2_t, a) * __builtin_bit_cast(half2_t, b) + c;
}

// ---------------- workspace layout (bytes) ----------------
static constexpr size_t OFF_XH  = 0;                 // 96*1024*12 u32 = 4,718,592
static constexpr size_t OFF_W0  = 4718592;           // w0A 40960 u32 = 163,840
static constexpr size_t OFF_BS0 = 4882432;           // 512 f32
static constexpr size_t OFF_W1L = 4884480;           // w1A 65536 u32 = 262,144
static constexpr size_t OFF_BS1 = 5146624;           // 512 f32
static constexpr size_t OFF_W2P = 5148672;           // 128*64 u32 = 32,768
static constexpr size_t OFF_ENC = 5181440;           // 1024*128 f32 = 524,288
static constexpr size_t OFF_YS0 = 5705728;           // 96*1024*128 half = 25,165,824
static constexpr size_t OFF_TPJ = 30871552;          // tprojG 6400 u32 = 25,600
static constexpr size_t OFF_HPJ = 30897152;          // hprojG 512 u32 = 2,048
static constexpr size_t OFF_CC  = 30899200;          // ccG 100 float2 = 800
// total ~30.9 MB

// ---------------- prep: pack [x_hist | emb] as fp16 pairs ----------------
__global__ void k_prep_xh(const float* __restrict__ xh, const int* __restrict__ tix,
                          const float* __restrict__ temb, uint32_t* __restrict__ out) {
  int idx = blockIdx.x * 256 + threadIdx.x;          // 96*1024*12 total
  if (idx >= 96 * 1024 * 12) return;
  int m = idx % 12;
  int tb = idx / 12;
  int b = tb & 1023, t = tb >> 10;
  int k0 = 2 * m, k1 = k0 + 1;
  float v0 = (k0 < 8) ? xh[(b * 96 + t) * 8 + k0] : temb[tix[b] * 16 + (k0 - 8)];
  float v1 = (k1 < 8) ? xh[(b * 96 + t) * 8 + k1] : temb[tix[b] * 16 + (k1 - 8)];
  out[idx] = pack2f(v0, v1);
}

// ---------------- prep: pack weights + k_diff tables ----------------
// A-fragment order for LSTM l: flat u32 idx = (((w*4+T)*NF + f)*64 + l)*4 + c
// content: lane l -> m=l&15, qf=l>>4; k = f*32 + qf*8 + 2c+{0,1};
// gate row g = (m&3)*128 + w*16 + (m>>2)*4 + T; K-cat = [x | h] (+ zero pad).
// tprojG[t][q][pi] = pack2f(W1_te(k0).te[t], W1_te(k0+1).te[t]) with
// k0 = (pi>>2)*32 + q*8 + (pi&3)*2; hprojG[s][k/2] pairs; ccG[t] = (cs*cd, cd).
__global__ void k_prep_w(const float* __restrict__ Wih0, const float* __restrict__ Whh0,
                         const float* __restrict__ bih0, const float* __restrict__ bhh0,
                         const float* __restrict__ Wih1, const float* __restrict__ Whh1,
                         const float* __restrict__ bih1, const float* __restrict__ bhh1,
                         const float* __restrict__ W2, const float* __restrict__ W1,
                         uint32_t* __restrict__ w0p, uint32_t* __restrict__ w1p,
                         uint32_t* __restrict__ w2p, float* __restrict__ bs0,
                         float* __restrict__ bs1, uint32_t* __restrict__ tpj,
                         uint32_t* __restrict__ hpj, float2* __restrict__ ccg) {
  int idx = blockIdx.x * 256 + threadIdx.x;
  if (idx < 40960) {                       // w0A: NF=5, K=160 ([x24|h128|pad8])
    int w = idx / 5120;
    int r = idx % 5120;
    int T = r / 1280; r %= 1280;
    int f = r / 256;  r %= 256;
    int l = r >> 2, c = r & 3;
    int m = l & 15, qf = l >> 4;
    int g = (m & 3) * 128 + w * 16 + (m >> 2) * 4 + T;
    int k0 = f * 32 + qf * 8 + 2 * c, k1 = k0 + 1;
    float a = (k0 < 24) ? Wih0[g * 24 + k0] : ((k0 < 152) ? Whh0[g * 128 + k0 - 24] : 0.f);
    float b = (k1 < 24) ? Wih0[g * 24 + k1] : ((k1 < 152) ? Whh0[g * 128 + k1 - 24] : 0.f);
    w0p[idx] = pack2f(a, b);
  } else if (idx < 106496) {               // w1A: NF=8, K=256 ([ys0 128|h128])
    int i = idx - 40960;
    int w = i / 8192;
    int r = i % 8192;
    int T = r / 2048; r %= 2048;
    int f = r / 256;  r %= 256;
    int l = r >> 2, c = r & 3;
    int m = l & 15, qf = l >> 4;
    int g = (m & 3) * 128 + w * 16 + (m >> 2) * 4 + T;
    int k0 = f * 32 + qf * 8 + 2 * c, k1 = k0 + 1;
    float a = (k0 < 128) ? Wih1[g * 128 + k0] : Whh1[g * 128 + k0 - 128];
    float b = (k1 < 128) ? Wih1[g * 128 + k1] : Whh1[g * 128 + k1 - 128];
    w1p[i] = pack2f(a, b);
  } else if (idx < 114688) {               // W2: 128 x 64 u32 (row-major pairs)
    int i = idx - 106496;
    w2p[i] = pack2f(W2[2 * i], W2[2 * i + 1]);
  } else if (idx < 115200) {
    int i = idx - 114688;
    bs0[i] = bih0[i] + bhh0[i];
  } else if (idx < 115712) {
    int i = idx - 115200;
    bs1[i] = bih1[i] + bhh1[i];
  } else if (idx < 122112) {               // tprojG: [t][q][pi] fragment order
    int i = idx - 115712;
    int t = i / 64;
    int r = i % 64;
    int q = r / 16, pi = r % 16;
    int k0 = (pi >> 2) * 32 + q * 8 + (pi & 3) * 2;
    float te[16];
#pragma unroll
    for (int j = 0; j < 8; j++) {
      float f = expf(-logf(10000.f) * (float)j / 8.f);
      float a = (float)t * f;
      te[j] = cosf(a);
      te[j + 8] = sinf(a);
    }
    float s0 = 0.f, s1 = 0.f;
#pragma unroll
    for (int j = 0; j < 16; j++) {
      s0 += W1[k0 * 184 + 152 + j] * te[j];
      s1 += W1[(k0 + 1) * 184 + 152 + j] * te[j];
    }
    // match the old path's fp16 storage rounding
    tpj[i] = pack2f((float)__half2float(__float2half_rn(s0)),
                    (float)__half2float(__float2half_rn(s1)));
  } else if (idx < 122624) {               // hprojG: [s][k/2] pairs
    int i = idx - 122112;
    int s = i / 64;
    int kp = i % 64;                       // pair index, k0 = 2*kp
    float te[16];
#pragma unroll
    for (int j = 0; j < 8; j++) {
      float f = expf(-logf(10000.f) * (float)j / 8.f);
      float a = (float)s * f;
      te[j] = cosf(a);
      te[j + 8] = sinf(a);
    }
    float s0 = 0.f, s1 = 0.f;
#pragma unroll
    for (int j = 0; j < 16; j++) {
      s0 += W1[(2 * kp) * 184 + 168 + j] * te[j];
      s1 += W1[(2 * kp + 1) * 184 + 168 + j] * te[j];
    }
    hpj[i] = pack2f((float)__half2float(__float2half_rn(s0)),
                    (float)__half2float(__float2half_rn(s1)));
  } else if (idx < 122724) {               // ccG = (cs*cd, cd)
    int qq = idx - 122624;
    float ab = 1.f, beta = 0.f;
    for (int i = 0; i <= qq; i++) {
      beta = 1e-4f + (0.02f - 1e-4f) * (float)i / 99.f;
      ab *= (1.f - beta);
    }
    float cs, cd;
    if (qq == 0) { cs = sqrtf(1.f - ab); cd = 1.f / (sqrtf(ab) + 1e-8f); }
    else { cs = beta / (sqrtf(1.f - ab) + 1e-8f); cd = 1.f / (sqrtf(1.f - beta) + 1e-8f); }
    ccg[qq] = make_float2(cs * cd, cd);
  }
}

// ---------------- LSTM layer 0 (MFMA; 16 batch/WG, 64 WGs x 512) ----------------
// in tile: [x(0..23) | h(24..151) | pad(152..159)], stride 160 halfs = 320 B.
__global__ __launch_bounds__(512, 2) void k_lstm0(const uint32_t* __restrict__ xh16,
                                                  const uint32_t* __restrict__ w0A,
                                                  const float* __restrict__ bs0,
                                                  __half* __restrict__ ys0) {
  __shared__ __align__(16) __half inb[2][16][160];
  const int tid = threadIdx.x;
  const int w = tid >> 6, l = tid & 63;
  const int n = l & 15, ql = l >> 4;
  const int ju = w * 16 + ql * 4;
  const int bbase = blockIdx.x * 16;

  uint4 Af[4][5];
#pragma unroll
  for (int T = 0; T < 4; T++)
#pragma unroll
    for (int f = 0; f < 5; f++)
      Af[T][f] = ((const uint4*)w0A)[((w * 4 + T) * 5 + f) * 64 + l];
  float bias[4][4];
#pragma unroll
  for (int T = 0; T < 4; T++)
#pragma unroll
    for (int r = 0; r < 4; r++) bias[T][r] = bs0[r * 128 + ju + T];

  for (int i = tid; i < 2560; i += 512) ((uint32_t*)inb)[i] = 0u;  // zero both bufs
  __syncthreads();
  if (tid < 192) {  // stage x_0 into buf 0
    int b = tid / 12, m = tid % 12;
    ((uint32_t*)&inb[0][b][0])[m] = xh16[(0 * 1024 + bbase + b) * 12 + m];
  }
  float cst[4] = {0.f, 0.f, 0.f, 0.f};
  __syncthreads();

  for (int t = 0; t < 96; t++) {
    const int cur = t & 1, nxt = cur ^ 1;
    uint32_t sx = 0;
    int sb = 0, sm = 0;
    if (t < 95 && tid < 192) {           // prefetch x_{t+1} under the MFMAs
      sb = tid / 12; sm = tid % 12;
      sx = xh16[((t + 1) * 1024 + bbase + sb) * 12 + sm];
    }
    v4f acc[4];
#pragma unroll
    for (int T = 0; T < 4; T++) acc[T] = (v4f){0.f, 0.f, 0.f, 0.f};
#pragma unroll
    for (int f = 0; f < 5; f++) {
      uint4 bu = *(const uint4*)&inb[cur][n][f * 32 + ql * 8];
      v8h Bv = __builtin_bit_cast(v8h, bu);
#pragma unroll
      for (int T = 0; T < 4; T++)
        acc[T] = __builtin_amdgcn_mfma_f32_16x16x32_f16(
            __builtin_bit_cast(v8h, Af[T][f]), Bv, acc[T], 0, 0, 0);
    }
    float hv[4];
#pragma unroll
    for (int T = 0; T < 4; T++) {
      float gi = acc[T][0] + bias[T][0];
      float gf = acc[T][1] + bias[T][1];
      float gg = acc[T][2] + bias[T][2];
      float go = acc[T][3] + bias[T][3];
      float c = sigm(gf) * cst[T] + sigm(gi) * tanh_f(gg);
      cst[T] = c;
      hv[T] = sigm(go) * tanh_f(c);
    }
    uint32_t h01 = pack2f(hv[0], hv[1]), h23 = pack2f(hv[2], hv[3]);
    *(uint2*)&inb[nxt][n][24 + ju] = make_uint2(h01, h23);
    *(uint2*)((__half*)ys0 + (size_t)(t * 1024 + bbase + n) * 128 + ju) = make_uint2(h01, h23);
    if (t < 95 && tid < 192) ((uint32_t*)&inb[nxt][sb][0])[sm] = sx;
    __syncthreads();
  }
}

// ---------------- LSTM layer 1 (MFMA; 16 batch/WG, 64 WGs x 512) ----------------
// in tile: [ys0_t(0..127) | h(128..255) | pad], stride 264 halfs = 528 B.
__global__ __launch_bounds__(512, 2) void k_lstm1(const uint32_t* __restrict__ ys0u,
                                                  const uint32_t* __restrict__ w1A,
                                                  const float* __restrict__ bs1,
                                                  float* __restrict__ enc) {
  __shared__ __align__(16) __half inb[2][16][264];
  const int tid = threadIdx.x;
  const int w = tid >> 6, l = tid & 63;
  const int n = l & 15, ql = l >> 4;
  const int ju = w * 16 + ql * 4;
  const int bbase = blockIdx.x * 16;
  const int sb = tid >> 5, sc = tid & 31;   // staging: batch, 8B-chunk

  uint4 Af[4][8];
#pragma unroll
  for (int T = 0; T < 4; T++)
#pragma unroll
    for (int f = 0; f < 8; f++)
      Af[T][f] = ((const uint4*)w1A)[((w * 4 + T) * 8 + f) * 64 + l];
  float bias[4][4];
#pragma unroll
  for (int T = 0; T < 4; T++)
#pragma unroll
    for (int r = 0; r < 4; r++) bias[T][r] = bs1[r * 128 + ju + T];

  for (int i = tid; i < 4224; i += 512) ((uint32_t*)inb)[i] = 0u;
  __syncthreads();
  {  // stage ys0[t=0] into buf 0
    uint2 v = ((const uint2*)ys0u)[(size_t)(0 * 1024 + bbase + sb) * 32 + sc];
    *(uint2*)&inb[0][sb][sc * 4] = v;
  }
  float cst[4] = {0.f, 0.f, 0.f, 0.f};
  __syncthreads();

  for (int t = 0; t < 96; t++) {
    const int cur = t & 1, nxt = cur ^ 1;
    uint2 sv = make_uint2(0u, 0u);
    if (t < 95)                          // prefetch ys0[t+1] under the MFMAs
      sv = ((const uint2*)ys0u)[(size_t)((t + 1) * 1024 + bbase + sb) * 32 + sc];
    v4f acc[4];
#pragma unroll
    for (int T = 0; T < 4; T++) acc[T] = (v4f){0.f, 0.f, 0.f, 0.f};
#pragma unroll
    for (int f = 0; f < 8; f++) {
      uint4 bu = *(const uint4*)&inb[cur][n][f * 32 + ql * 8];
      v8h Bv = __builtin_bit_cast(v8h, bu);
#pragma unroll
      for (int T = 0; T < 4; T++)
        acc[T] = __builtin_amdgcn_mfma_f32_16x16x32_f16(
            __builtin_bit_cast(v8h, Af[T][f]), Bv, acc[T], 0, 0, 0);
    }
    float hv[4];
#pragma unroll
    for (int T = 0; T < 4; T++) {
      float gi = acc[T][0] + bias[T][0];
      float gf = acc[T][1] + bias[T][1];
      float gg = acc[T][2] + bias[T][2];
      float go = acc[T][3] + bias[T][3];
      float c = sigm(gf) * cst[T] + sigm(gi) * tanh_f(gg);
      cst[T] = c;
      hv[T] = sigm(go) * tanh_f(c);
    }
    *(uint2*)&inb[nxt][n][128 + ju] = make_uint2(pack2f(hv[0], hv[1]), pack2f(hv[2], hv[3]));
    if (t < 95) *(uint2*)&inb[nxt][sb][sc * 4] = sv;
    if (t == 95)
      *(float4*)&enc[(size_t)(bbase + n) * 128 + ju] = make_float4(hv[0], hv[1], hv[2], hv[3]);
    __syncthreads();
  }
}

// ---------------- AR diffusion: DUAL-CHAIN 4-wave M-split, 32 batches/WG ----
// W1 cols: [0:128) enc | [128:134) exo | [134:150) emb | 150 prev_y | 151 y |
//          [152:168) t_e | [168:184) h_e
// Round 14: each WG advances two independent 16-batch chains (A: gbase+m,
// B: gbase+16+m) per barrier. Wave w owns W2 tiles {2w,2w+1} for BOTH
// chains (16 MFMAs/step-pair). tproj/cc shared (lockstep t). One barrier
// per step-pair; partL[buf][chain][m][slot]; bt updates for both chains in
// the post-barrier ds_read shadow.
__global__ __launch_bounds__(256, 1) void k_diff(
    const float* __restrict__ xfut, const float* __restrict__ y0,
    const int* __restrict__ tix, const float* __restrict__ noise,
    const float* __restrict__ temb, const float* __restrict__ W1,
    const float* __restrict__ b1, const float* __restrict__ b2,
    const float* __restrict__ W3, const float* __restrict__ b3,
    const uint32_t* __restrict__ w2p, const float* __restrict__ enc,
    const uint32_t* __restrict__ tpj, const uint32_t* __restrict__ hpj,
    const float2* __restrict__ ccG, float* __restrict__ out) {
  __shared__ uint32_t W1sL[128 * 65];                 // W1 cols 0..127 (stride 65)
  __shared__ uint32_t W1xL[128 * 29];                 // W1 cols 128..183 (stride 29)
  __shared__ uint32_t encPL[32 * 65];                 // enc fp16 pairs, 32 batches
  __shared__ uint32_t embPL[32 * 9];                  // emb fp16 pairs, 32 batches
  __shared__ uint32_t encdL[2][256 * 17];             // per-thread 16 pairs x 2 chains
  __shared__ __align__(16) float partL[2][2][16][20]; // [buf][chain][m][slot] (+pad)

  const int tid = threadIdx.x;
  const int w = tid >> 6, l = tid & 63;
  const int m = l & 15, q = l >> 4;
  const int gbase = blockIdx.x * 32;                  // 32 batches per WG
  const uint4* tpj4 = (const uint4*)tpj;

  // ---- stage W1 / enc / emb ----
  for (int i = tid; i < 128 * 64; i += 256) {
    int r = i >> 6, c = i & 63;
    W1sL[r * 65 + c] = pack2f(W1[r * 184 + 2 * c], W1[r * 184 + 2 * c + 1]);
  }
  for (int i = tid; i < 128 * 28; i += 256) {
    int r = i / 28, c = i % 28;
    W1xL[r * 29 + c] = pack2f(W1[r * 184 + 128 + 2 * c], W1[r * 184 + 129 + 2 * c]);
  }
  for (int i = tid; i < 32 * 64; i += 256) {
    int bq = i >> 6, c = i & 63;
    encPL[bq * 65 + c] = pack2f(enc[(gbase + bq) * 128 + 2 * c],
                                enc[(gbase + bq) * 128 + 2 * c + 1]);
  }
  for (int i = tid; i < 32 * 8; i += 256) {
    int bq = i >> 3, c = i & 7;
    const float* er = temb + tix[gbase + bq] * 16;
    embPL[bq * 9 + c] = pack2f(er[2 * c], er[2 * c + 1]);
  }
  __syncthreads();

  // ---- per-lane constant part of base, both chains ----
#pragma unroll
  for (int ch = 0; ch < 2; ch++) {
    const int bm = ch * 16 + m;
    for (int pi = 0; pi < 16; pi++) {
      int k0 = (pi >> 2) * 32 + q * 8 + (pi & 3) * 2;
      half2_t a0 = {(_Float16)0.f, (_Float16)0.f};
      half2_t a1 = a0;
      const uint32_t* wr0 = &W1sL[k0 * 65];
      const uint32_t* wr1 = &W1sL[(k0 + 1) * 65];
      const uint32_t* ep = &encPL[bm * 65];
#pragma unroll 8
      for (int c = 0; c < 64; c++) {
        half2_t e = __builtin_bit_cast(half2_t, ep[c]);
        a0 += __builtin_bit_cast(half2_t, wr0[c]) * e;
        a1 += __builtin_bit_cast(half2_t, wr1[c]) * e;
      }
#pragma unroll
      for (int c = 0; c < 8; c++) {
        half2_t e = __builtin_bit_cast(half2_t, embPL[bm * 9 + c]);
        a0 += __builtin_bit_cast(half2_t, W1xL[k0 * 29 + 3 + c]) * e;     // cols 134..149
        a1 += __builtin_bit_cast(half2_t, W1xL[(k0 + 1) * 29 + 3 + c]) * e;
      }
      float e0 = b1[k0] + (float)a0.x + (float)a0.y;
      float e1 = b1[k0 + 1] + (float)a1.x + (float)a1.y;
      encdL[ch][tid * 17 + pi] = pack2f(e0, e1);
    }
  }

  // ---- per-wave resident: W2 tiles {2w, 2w+1}, packed b2/W3 for them ----
  uint4 Bf[2][4];
  {
    const uint4* w2u4 = (const uint4*)w2p;
#pragma unroll
    for (int j = 0; j < 2; j++)
#pragma unroll
      for (int f = 0; f < 4; f++)
        Bf[j][f] = w2u4[((2 * w + j) * 16 + m) * 16 + f * 4 + q];
  }
  uint32_t b2P[4], w3P[4];
#pragma unroll
  for (int j = 0; j < 2; j++) {
    int tt = 2 * w + j;
    b2P[2 * j]     = pack2f(b2[tt * 16 + q * 4 + 0], b2[tt * 16 + q * 4 + 1]);
    b2P[2 * j + 1] = pack2f(b2[tt * 16 + q * 4 + 2], b2[tt * 16 + q * 4 + 3]);
    w3P[2 * j]     = pack2f(W3[tt * 16 + q * 4 + 0], W3[tt * 16 + q * 4 + 1]);
    w3P[2 * j + 1] = pack2f(W3[tt * 16 + q * 4 + 2], W3[tt * 16 + q * 4 + 3]);
  }
  const float b3v = b3[0];
  const int pslot = w * 4 + q;                      // partL column

  uint32_t w1yP[16];
#pragma unroll
  for (int pi = 0; pi < 16; pi++) {
    int k0 = (pi >> 2) * 32 + q * 8 + (pi & 3) * 2;
    uint32_t ua = W1xL[k0 * 29 + 11];         // halfs: col150(lo), col151(hi)
    uint32_t ub = W1xL[(k0 + 1) * 29 + 11];
    w1yP[pi] = (ua >> 16) | (ub & 0xFFFF0000u);
  }

  float prevA = y0[gbase + m];
  float prevB = y0[gbase + 16 + m];
  __syncthreads();

  float yA = 0.f, yB = 0.f;
  float2 ccv = make_float2(0.f, 0.f);    // (cs*cd, cd) of current step
  uint32_t bphA[16], btA[16], bphB[16], btB[16];
  const v4f zf = (v4f){0.f, 0.f, 0.f, 0.f};

// compute one chain's MFMA + epilogue into partL[PB][CH]; AU/BT per chain.
#define CHAIN_COMPUTE(Y, BT, CH, PB)                                           \
  do {                                                                         \
    const uint32_t yP = cvtpk(Y);                                              \
    uint4 au[4];                                                               \
    _Pragma("unroll")                                                          \
    for (int f = 0; f < 4; f++) {                                              \
      au[f].x = pk_relufma(w1yP[4 * f + 0], yP, BT[4 * f + 0]);                \
      au[f].y = pk_relufma(w1yP[4 * f + 1], yP, BT[4 * f + 1]);                \
      au[f].z = pk_relufma(w1yP[4 * f + 2], yP, BT[4 * f + 2]);                \
      au[f].w = pk_relufma(w1yP[4 * f + 3], yP, BT[4 * f + 3]);                \
    }                                                                          \
    v4f a0 = __builtin_amdgcn_mfma_f32_16x16x32_f16(                           \
        __builtin_bit_cast(v8h, Bf[0][0]), __builtin_bit_cast(v8h, au[0]), zf, 0, 0, 0); \
    v4f b0 = __builtin_amdgcn_mfma_f32_16x16x32_f16(                           \
        __builtin_bit_cast(v8h, Bf[0][1]), __builtin_bit_cast(v8h, au[1]), zf, 0, 0, 0); \
    v4f a1 = __builtin_amdgcn_mfma_f32_16x16x32_f16(                           \
        __builtin_bit_cast(v8h, Bf[1][0]), __builtin_bit_cast(v8h, au[0]), zf, 0, 0, 0); \
    v4f b1x = __builtin_amdgcn_mfma_f32_16x16x32_f16(                          \
        __builtin_bit_cast(v8h, Bf[1][1]), __builtin_bit_cast(v8h, au[1]), zf, 0, 0, 0); \
    a0 = __builtin_amdgcn_mfma_f32_16x16x32_f16(                               \
        __builtin_bit_cast(v8h, Bf[0][2]), __builtin_bit_cast(v8h, au[2]), a0, 0, 0, 0); \
    b0 = __builtin_amdgcn_mfma_f32_16x16x32_f16(                               \
        __builtin_bit_cast(v8h, Bf[0][3]), __builtin_bit_cast(v8h, au[3]), b0, 0, 0, 0); \
    a1 = __builtin_amdgcn_mfma_f32_16x16x32_f16(                               \
        __builtin_bit_cast(v8h, Bf[1][2]), __builtin_bit_cast(v8h, au[2]), a1, 0, 0, 0); \
    b1x = __builtin_amdgcn_mfma_f32_16x16x32_f16(                              \
        __builtin_bit_cast(v8h, Bf[1][3]), __builtin_bit_cast(v8h, au[3]), b1x, 0, 0, 0); \
    v4f c0 = a0 + b0, c1 = a1 + b1x;                                           \
    half2_t runA = {(_Float16)0.f, (_Float16)0.f};                             \
    half2_t runB = runA;                                                       \
    {                                                                          \
      uint32_t h01 = pk_max0(pk_add(cvtpk2(c0[0], c0[1]), b2P[0]));            \
      uint32_t h23 = pk_max0(pk_add(cvtpk2(c0[2], c0[3]), b2P[1]));            \
      runA = pk_fma2(h01, w3P[0], runA);                                       \
      runA = pk_fma2(h23, w3P[1], runA);                                       \
      uint32_t g01 = pk_max0(pk_add(cvtpk2(c1[0], c1[1]), b2P[2]));            \
      uint32_t g23 = pk_max0(pk_add(cvtpk2(c1[2], c1[3]), b2P[3]));            \
      runB = pk_fma2(g01, w3P[2], runB);                                       \
      runB = pk_fma2(g23, w3P[3], runB);                                       \
    }                                                                          \
    partL[PB][CH][m][pslot] = ((float)runA.x + (float)runA.y) +                \
                              ((float)runB.x + (float)runB.y);                 \
  } while (0)

// dual-chain step at t_: advances chain A and chain B with ONE barrier.
#define DSTEP(t_, PB)                                                          \
  do {                                                                         \
    const int tn_ = ((t_) > 0) ? (t_) - 1 : 0;                                 \
    const uint4* tg_ = tpj4 + (size_t)(tn_ * 4 + q) * 4;   /* shared */        \
    uint4 t0 = tg_[0], t1 = tg_[1], t2 = tg_[2], t3 = tg_[3];                  \
    float2 cck_ = ccG[tn_];                                                    \
    CHAIN_COMPUTE(yA, btA, 0, PB);                                             \
    CHAIN_COMPUTE(yB, btB, 1, PB);                                             \
    const float preA_ = ccv.y * yA - ccv.x * b3v;                              \
    const float preB_ = ccv.y * yB - ccv.x * b3v;                              \
    __syncthreads();                                                           \
    const v4f* plA_ = (const v4f*)&partL[PB][0][m][0];                         \
    v4f pA0_ = plA_[0], pA1_ = plA_[1], pA2_ = plA_[2], pA3_ = plA_[3];        \
    const v4f* plB_ = (const v4f*)&partL[PB][1][m][0];                         \
    v4f pB0_ = plB_[0], pB1_ = plB_[1], pB2_ = plB_[2], pB3_ = plB_[3];        \
    btA[0] = pk_add(bphA[0], t0.x);   btA[1] = pk_add(bphA[1], t0.y);          \
    btA[2] = pk_add(bphA[2], t0.z);   btA[3] = pk_add(bphA[3], t0.w);          \
    btA[4] = pk_add(bphA[4], t1.x);   btA[5] = pk_add(bphA[5], t1.y);          \
    btA[6] = pk_add(bphA[6], t1.z);   btA[7] = pk_add(bphA[7], t1.w);          \
    btA[8] = pk_add(bphA[8], t2.x);   btA[9] = pk_add(bphA[9], t2.y);          \
    btA[10] = pk_add(bphA[10], t2.z); btA[11] = pk_add(bphA[11], t2.w);        \
    btA[12] = pk_add(bphA[12], t3.x); btA[13] = pk_add(bphA[13], t3.y);        \
    btA[14] = pk_add(bphA[14], t3.z); btA[15] = pk_add(bphA[15], t3.w);        \
    btB[0] = pk_add(bphB[0], t0.x);   btB[1] = pk_add(bphB[1], t0.y);          \
    btB[2] = pk_add(bphB[2], t0.z);   btB[3] = pk_add(bphB[3], t0.w);          \
    btB[4] = pk_add(bphB[4], t1.x);   btB[5] = pk_add(bphB[5], t1.y);          \
    btB[6] = pk_add(bphB[6], t1.z);   btB[7] = pk_add(bphB[7], t1.w);          \
    btB[8] = pk_add(bphB[8], t2.x);   btB[9] = pk_add(bphB[9], t2.y);          \
    btB[10] = pk_add(bphB[10], t2.z); btB[11] = pk_add(bphB[11], t2.w);        \
    btB[12] = pk_add(bphB[12], t3.x); btB[13] = pk_add(bphB[13], t3.y);        \
    btB[14] = pk_add(bphB[14], t3.z); btB[15] = pk_add(bphB[15], t3.w);        \
    v4f psA_ = (pA0_ + pA1_) + (pA2_ + pA3_);                                  \
    v4f psB_ = (pB0_ + pB1_) + (pB2_ + pB3_);                                  \
    yA = preA_ - ccv.x * ((psA_[0] + psA_[1]) + (psA_[2] + psA_[3]));          \
    yB = preB_ - ccv.x * ((psB_[0] + psB_[1]) + (psB_[2] + psB_[3]));          \
    ccv = cck_;                                                                \
  } while (0)

  for (int s = 0; s < 8; s++) {
    float ynA = noise[s * 1024 + gbase + m];
    float ynB = noise[s * 1024 + gbase + 16 + m];
    // base pairs for this AR step, both chains
    float xfA[6], xfB[6];
#pragma unroll
    for (int i = 0; i < 6; i++) {
      xfA[i] = xfut[((gbase + m) * 8 + s) * 6 + i];
      xfB[i] = xfut[((gbase + 16 + m) * 8 + s) * 6 + i];
    }
#pragma unroll
    for (int pi = 0; pi < 16; pi++) {
      int k0 = (pi >> 2) * 32 + q * 8 + (pi & 3) * 2;
      float2 hh = up2(hpj[s * 64 + (k0 >> 1)]);
      float2 edA = up2(encdL[0][tid * 17 + pi]);
      float2 edB = up2(encdL[1][tid * 17 + pi]);
      float eA0 = edA.x + hh.x, eA1 = edA.y + hh.y;
      float eB0 = edB.x + hh.x, eB1 = edB.y + hh.y;
#pragma unroll
      for (int c = 0; c < 3; c++) {
        float2 w0v = up2(W1xL[k0 * 29 + c]);        // cols 128..133 (exo)
        float2 w1v = up2(W1xL[(k0 + 1) * 29 + c]);
        eA0 += w0v.x * xfA[2 * c] + w0v.y * xfA[2 * c + 1];
        eA1 += w1v.x * xfA[2 * c] + w1v.y * xfA[2 * c + 1];
        eB0 += w0v.x * xfB[2 * c] + w0v.y * xfB[2 * c + 1];
        eB1 += w1v.x * xfB[2 * c] + w1v.y * xfB[2 * c + 1];
      }
      float wy0 = up2(W1xL[k0 * 29 + 11]).x;        // col 150
      float wy1 = up2(W1xL[(k0 + 1) * 29 + 11]).x;
      eA0 += wy0 * prevA;  eA1 += wy1 * prevA;
      eB0 += wy0 * prevB;  eB1 += wy1 * prevB;
      bphA[pi] = pack2f(eA0, eA1);
      bphB[pi] = pack2f(eB0, eB1);
    }

    yA = ynA;
    yB = ynB;
    {  // bt = bph + tproj[99], both chains
      const uint4* tg = tpj4 + (size_t)(99 * 4 + q) * 4;
      uint4 t0 = tg[0], t1 = tg[1], t2 = tg[2], t3 = tg[3];
      btA[0] = pk_add(bphA[0], t0.x);   btA[1] = pk_add(bphA[1], t0.y);
      btA[2] = pk_add(bphA[2], t0.z);   btA[3] = pk_add(bphA[3], t0.w);
      btA[4] = pk_add(bphA[4], t1.x);   btA[5] = pk_add(bphA[5], t1.y);
      btA[6] = pk_add(bphA[6], t1.z);   btA[7] = pk_add(bphA[7], t1.w);
      btA[8] = pk_add(bphA[8], t2.x);   btA[9] = pk_add(bphA[9], t2.y);
      btA[10] = pk_add(bphA[10], t2.z); btA[11] = pk_add(bphA[11], t2.w);
      btA[12] = pk_add(bphA[12], t3.x); btA[13] = pk_add(bphA[13], t3.y);
      btA[14] = pk_add(bphA[14], t3.z); btA[15] = pk_add(bphA[15], t3.w);
      btB[0] = pk_add(bphB[0], t0.x);   btB[1] = pk_add(bphB[1], t0.y);
      btB[2] = pk_add(bphB[2], t0.z);   btB[3] = pk_add(bphB[3], t0.w);
      btB[4] = pk_add(bphB[4], t1.x);   btB[5] = pk_add(bphB[5], t1.y);
      btB[6] = pk_add(bphB[6], t1.z);   btB[7] = pk_add(bphB[7], t1.w);
      btB[8] = pk_add(bphB[8], t2.x);   btB[9] = pk_add(bphB[9], t2.y);
      btB[10] = pk_add(bphB[10], t2.z); btB[11] = pk_add(bphB[11], t2.w);
      btB[12] = pk_add(bphB[12], t3.x); btB[13] = pk_add(bphB[13], t3.y);
      btB[14] = pk_add(bphB[14], t3.z); btB[15] = pk_add(bphB[15], t3.w);
    }
    ccv = ccG[99];

    for (int it = 0; it < 50; it++) {   // 100 steps, partL buffer ping-pong
      DSTEP(99 - 2 * it, 0);
      DSTEP(98 - 2 * it, 1);
    }

    if (w == 0 && l < 16) out[(gbase + l) * 8 + s] = yA;
    if (w == 1 && l < 16) out[(gbase + 16 + l) * 8 + s] = yB;
    prevA = yA;
    prevB = yB;
  }
#undef DSTEP
#undef CHAIN_COMPUTE
}

// ---------------------------------------------------------------------------
extern "C" void kernel_launch(void* const* d_in, const int* in_sizes, int n_in,
                              void* d_out, int out_size, void* d_ws, size_t ws_size,
                              hipStream_t stream) {
  const float* x_hist    = (const float*)d_in[0];
  const float* x_future  = (const float*)d_in[1];
  const float* y0        = (const float*)d_in[2];
  const int*   turb_idx  = (const int*)d_in[3];
  const float* init_noise = (const float*)d_in[5];
  const float* turb_emb  = (const float*)d_in[6];
  const float* W_ih0     = (const float*)d_in[7];
  const float* W_hh0     = (const float*)d_in[8];
  const float* b_ih0     = (const float*)d_in[9];
  const float* b_hh0     = (const float*)d_in[10];
  const float* W_ih1     = (const float*)d_in[11];
  const float* W_hh1     = (const float*)d_in[12];
  const float* b_ih1     = (const float*)d_in[13];
  const float* b_hh1     = (const float*)d_in[14];
  const float* W1        = (const float*)d_in[15];
  const float* b1        = (const float*)d_in[16];
  const float* W2        = (const float*)d_in[17];
  const float* b2        = (const float*)d_in[18];
  const float* W3        = (const float*)d_in[19];
  const float* b3        = (const float*)d_in[20];

  char* ws = (char*)d_ws;
  uint32_t* xh16 = (uint32_t*)(ws + OFF_XH);
  uint32_t* w0p  = (uint32_t*)(ws + OFF_W0);
  float*    bs0  = (float*)(ws + OFF_BS0);
  uint32_t* w1p  = (uint32_t*)(ws + OFF_W1L);
  float*    bs1  = (float*)(ws + OFF_BS1);
  uint32_t* w2p  = (uint32_t*)(ws + OFF_W2P);
  float*    encf = (float*)(ws + OFF_ENC);
  __half*   ys0h = (__half*)(ws + OFF_YS0);
  uint32_t* tpjw = (uint32_t*)(ws + OFF_TPJ);
  uint32_t* hpjw = (uint32_t*)(ws + OFF_HPJ);
  float2*   ccw  = (float2*)(ws + OFF_CC);

  k_prep_xh<<<4608, 256, 0, stream>>>(x_hist, turb_idx, turb_emb, xh16);
  k_prep_w<<<480, 256, 0, stream>>>(W_ih0, W_hh0, b_ih0, b_hh0,
                                    W_ih1, W_hh1, b_ih1, b_hh1,
                                    W2, W1, w0p, w1p, w2p, bs0, bs1,
                                    tpjw, hpjw, ccw);
  k_lstm0<<<64, 512, 0, stream>>>(xh16, w0p, bs0, ys0h);
  k_lstm1<<<64, 512, 0, stream>>>((const uint32_t*)ys0h, w1p, bs1, encf);
  k_diff<<<32, 256, 0, stream>>>(x_future, y0, turb_idx, init_noise, turb_emb,
                                 W1, b1, b2, W3, b3, w2p, encf,
                                 tpjw, hpjw, ccw, (float*)d_out);
}

// Round 10
// 632.655 us; speedup vs baseline: 1.3549x; 1.3549x over previous
//
#include <hip/hip_runtime.h>
#include <hip/hip_fp16.h>
#include <stdint.h>

// ---------------------------------------------------------------------------
// Seq2SeqARDiffusion on MI355X.
//   k_prep_xh : pack [x_hist|emb] fp16 inputs for LSTM0, layout [t][b][12 u32]
//   k_prep_w  : pack LSTM weights into MFMA A-fragment order (+ W2, bias sums,
//               + tprojG/hprojG/ccG tables in k_diff fragment order)
//   k_lstm0   : persistent MFMA LSTM layer 0, 64 WGs x 512 thr, 16 batch/WG
//   k_lstm1   : persistent MFMA LSTM layer 1 -> enc_out, same structure
//   k_diff    : round-15 = REVERT to round-11 exactly (measured best: 634us
//               total, k_diff 333us). Post-r14 conclusion: the step is
//               per-chain dependent-latency bound (~670cy chain latency +
//               ~330cy barrier overhead); all structural variants tried
//               (2-wave, 1-wave barrier-free, AGPR pin, light-barrier,
//               MFMA chain splits, dual-chain ILP) measured WORSE. r11 is
//               the floor of this decomposition.
// ---------------------------------------------------------------------------

typedef __attribute__((ext_vector_type(2))) _Float16 half2_t;
typedef __attribute__((ext_vector_type(8))) _Float16 v8h;
typedef __attribute__((ext_vector_type(4))) float v4f;

#define DEV __device__ __forceinline__

DEV uint32_t pack2f(float a, float b) {
  __half ha = __float2half_rn(a), hb = __float2half_rn(b);
  return (uint32_t)__half_as_ushort(ha) | ((uint32_t)__half_as_ushort(hb) << 16);
}

DEV float2 up2(uint32_t u) {
  half2_t h = __builtin_bit_cast(half2_t, u);
  return make_float2((float)h.x, (float)h.y);
}

DEV float fast_ex2(float x) {
#if __has_builtin(__builtin_amdgcn_exp2f)
  return __builtin_amdgcn_exp2f(x);
#else
  return exp2f(x);
#endif
}
DEV float fast_rcp(float x) {
#if __has_builtin(__builtin_amdgcn_rcpf)
  return __builtin_amdgcn_rcpf(x);
#else
  return 1.f / x;
#endif
}
DEV float sigm(float x) { return fast_rcp(1.f + fast_ex2(-1.4426950408889634f * x)); }
DEV float tanh_f(float x) {
  return 2.f * fast_rcp(1.f + fast_ex2(-2.8853900817779268f * x)) - 1.f;
}

DEV uint32_t pk_add(uint32_t a, uint32_t b) {
  return __builtin_bit_cast(uint32_t,
      __builtin_bit_cast(half2_t, a) + __builtin_bit_cast(half2_t, b));
}

// relu(w*y + b), packed fp16
DEV uint32_t pk_relufma(uint32_t w, uint32_t y, uint32_t b) {
  half2_t r = __builtin_bit_cast(half2_t, w) * __builtin_bit_cast(half2_t, y) +
              __builtin_bit_cast(half2_t, b);
  half2_t z = {(_Float16)0.f, (_Float16)0.f};
#if __has_builtin(__builtin_elementwise_max)
  r = __builtin_elementwise_max(r, z);
#else
  uint32_t u = __builtin_bit_cast(uint32_t, r);
  uint32_t mask = ((u >> 15) & 1u) * 0xFFFFu | ((u >> 31) & 1u) * 0xFFFF0000u;
  r = __builtin_bit_cast(half2_t, u & ~mask);
#endif
  return __builtin_bit_cast(uint32_t, r);
}

DEV uint32_t pk_max0(uint32_t a) {
  half2_t z = {(_Float16)0.f, (_Float16)0.f};
#if __has_builtin(__builtin_elementwise_max)
  return __builtin_bit_cast(uint32_t,
      __builtin_elementwise_max(__builtin_bit_cast(half2_t, a), z));
#else
  uint32_t mask = ((a >> 15) & 1u) * 0xFFFFu | ((a >> 31) & 1u) * 0xFFFF0000u;
  return a & ~mask;
#endif
}

DEV uint32_t cvtpk(float y) {
#if __has_builtin(__builtin_amdgcn_cvt_pkrtz)
  return __builtin_bit_cast(uint32_t, __builtin_amdgcn_cvt_pkrtz(y, y));
#else
  return pack2f(y, y);
#endif
}

DEV uint32_t cvtpk2(float a, float b) {
#if __has_builtin(__builtin_amdgcn_cvt_pkrtz)
  return __builtin_bit_cast(uint32_t, __builtin_amdgcn_cvt_pkrtz(a, b));
#else
  return pack2f(a, b);
#endif
}

DEV half2_t pk_fma2(uint32_t a, uint32_t b, half2_t c) {
  return __builtin_bit_cast(half2_t, a) * __builtin_bit_cast(half2_t, b) + c;
}

// ---------------- workspace layout (bytes) ----------------
static constexpr size_t OFF_XH  = 0;                 // 96*1024*12 u32 = 4,718,592
static constexpr size_t OFF_W0  = 4718592;           // w0A 40960 u32 = 163,840
static constexpr size_t OFF_BS0 = 4882432;           // 512 f32
static constexpr size_t OFF_W1L = 4884480;           // w1A 65536 u32 = 262,144
static constexpr size_t OFF_BS1 = 5146624;           // 512 f32
static constexpr size_t OFF_W2P = 5148672;           // 128*64 u32 = 32,768
static constexpr size_t OFF_ENC = 5181440;           // 1024*128 f32 = 524,288
static constexpr size_t OFF_YS0 = 5705728;           // 96*1024*128 half = 25,165,824
static constexpr size_t OFF_TPJ = 30871552;          // tprojG 6400 u32 = 25,600
static constexpr size_t OFF_HPJ = 30897152;          // hprojG 512 u32 = 2,048
static constexpr size_t OFF_CC  = 30899200;          // ccG 100 float2 = 800
// total ~30.9 MB

// ---------------- prep: pack [x_hist | emb] as fp16 pairs ----------------
__global__ void k_prep_xh(const float* __restrict__ xh, const int* __restrict__ tix,
                          const float* __restrict__ temb, uint32_t* __restrict__ out) {
  int idx = blockIdx.x * 256 + threadIdx.x;          // 96*1024*12 total
  if (idx >= 96 * 1024 * 12) return;
  int m = idx % 12;
  int tb = idx / 12;
  int b = tb & 1023, t = tb >> 10;
  int k0 = 2 * m, k1 = k0 + 1;
  float v0 = (k0 < 8) ? xh[(b * 96 + t) * 8 + k0] : temb[tix[b] * 16 + (k0 - 8)];
  float v1 = (k1 < 8) ? xh[(b * 96 + t) * 8 + k1] : temb[tix[b] * 16 + (k1 - 8)];
  out[idx] = pack2f(v0, v1);
}

// ---------------- prep: pack weights + k_diff tables ----------------
// A-fragment order for LSTM l: flat u32 idx = (((w*4+T)*NF + f)*64 + l)*4 + c
// content: lane l -> m=l&15, qf=l>>4; k = f*32 + qf*8 + 2c+{0,1};
// gate row g = (m&3)*128 + w*16 + (m>>2)*4 + T; K-cat = [x | h] (+ zero pad).
// tprojG[t][q][pi] = pack2f(W1_te(k0).te[t], W1_te(k0+1).te[t]) with
// k0 = (pi>>2)*32 + q*8 + (pi&3)*2; hprojG[s][k/2] pairs; ccG[t] = (cs*cd, cd).
__global__ void k_prep_w(const float* __restrict__ Wih0, const float* __restrict__ Whh0,
                         const float* __restrict__ bih0, const float* __restrict__ bhh0,
                         const float* __restrict__ Wih1, const float* __restrict__ Whh1,
                         const float* __restrict__ bih1, const float* __restrict__ bhh1,
                         const float* __restrict__ W2, const float* __restrict__ W1,
                         uint32_t* __restrict__ w0p, uint32_t* __restrict__ w1p,
                         uint32_t* __restrict__ w2p, float* __restrict__ bs0,
                         float* __restrict__ bs1, uint32_t* __restrict__ tpj,
                         uint32_t* __restrict__ hpj, float2* __restrict__ ccg) {
  int idx = blockIdx.x * 256 + threadIdx.x;
  if (idx < 40960) {                       // w0A: NF=5, K=160 ([x24|h128|pad8])
    int w = idx / 5120;
    int r = idx % 5120;
    int T = r / 1280; r %= 1280;
    int f = r / 256;  r %= 256;
    int l = r >> 2, c = r & 3;
    int m = l & 15, qf = l >> 4;
    int g = (m & 3) * 128 + w * 16 + (m >> 2) * 4 + T;
    int k0 = f * 32 + qf * 8 + 2 * c, k1 = k0 + 1;
    float a = (k0 < 24) ? Wih0[g * 24 + k0] : ((k0 < 152) ? Whh0[g * 128 + k0 - 24] : 0.f);
    float b = (k1 < 24) ? Wih0[g * 24 + k1] : ((k1 < 152) ? Whh0[g * 128 + k1 - 24] : 0.f);
    w0p[idx] = pack2f(a, b);
  } else if (idx < 106496) {               // w1A: NF=8, K=256 ([ys0 128|h128])
    int i = idx - 40960;
    int w = i / 8192;
    int r = i % 8192;
    int T = r / 2048; r %= 2048;
    int f = r / 256;  r %= 256;
    int l = r >> 2, c = r & 3;
    int m = l & 15, qf = l >> 4;
    int g = (m & 3) * 128 + w * 16 + (m >> 2) * 4 + T;
    int k0 = f * 32 + qf * 8 + 2 * c, k1 = k0 + 1;
    float a = (k0 < 128) ? Wih1[g * 128 + k0] : Whh1[g * 128 + k0 - 128];
    float b = (k1 < 128) ? Wih1[g * 128 + k1] : Whh1[g * 128 + k1 - 128];
    w1p[i] = pack2f(a, b);
  } else if (idx < 114688) {               // W2: 128 x 64 u32 (row-major pairs)
    int i = idx - 106496;
    w2p[i] = pack2f(W2[2 * i], W2[2 * i + 1]);
  } else if (idx < 115200) {
    int i = idx - 114688;
    bs0[i] = bih0[i] + bhh0[i];
  } else if (idx < 115712) {
    int i = idx - 115200;
    bs1[i] = bih1[i] + bhh1[i];
  } else if (idx < 122112) {               // tprojG: [t][q][pi] fragment order
    int i = idx - 115712;
    int t = i / 64;
    int r = i % 64;
    int q = r / 16, pi = r % 16;
    int k0 = (pi >> 2) * 32 + q * 8 + (pi & 3) * 2;
    float te[16];
#pragma unroll
    for (int j = 0; j < 8; j++) {
      float f = expf(-logf(10000.f) * (float)j / 8.f);
      float a = (float)t * f;
      te[j] = cosf(a);
      te[j + 8] = sinf(a);
    }
    float s0 = 0.f, s1 = 0.f;
#pragma unroll
    for (int j = 0; j < 16; j++) {
      s0 += W1[k0 * 184 + 152 + j] * te[j];
      s1 += W1[(k0 + 1) * 184 + 152 + j] * te[j];
    }
    // match the old path's fp16 storage rounding
    tpj[i] = pack2f((float)__half2float(__float2half_rn(s0)),
                    (float)__half2float(__float2half_rn(s1)));
  } else if (idx < 122624) {               // hprojG: [s][k/2] pairs
    int i = idx - 122112;
    int s = i / 64;
    int kp = i % 64;                       // pair index, k0 = 2*kp
    float te[16];
#pragma unroll
    for (int j = 0; j < 8; j++) {
      float f = expf(-logf(10000.f) * (float)j / 8.f);
      float a = (float)s * f;
      te[j] = cosf(a);
      te[j + 8] = sinf(a);
    }
    float s0 = 0.f, s1 = 0.f;
#pragma unroll
    for (int j = 0; j < 16; j++) {
      s0 += W1[(2 * kp) * 184 + 168 + j] * te[j];
      s1 += W1[(2 * kp + 1) * 184 + 168 + j] * te[j];
    }
    hpj[i] = pack2f((float)__half2float(__float2half_rn(s0)),
                    (float)__half2float(__float2half_rn(s1)));
  } else if (idx < 122724) {               // ccG = (cs*cd, cd)
    int qq = idx - 122624;
    float ab = 1.f, beta = 0.f;
    for (int i = 0; i <= qq; i++) {
      beta = 1e-4f + (0.02f - 1e-4f) * (float)i / 99.f;
      ab *= (1.f - beta);
    }
    float cs, cd;
    if (qq == 0) { cs = sqrtf(1.f - ab); cd = 1.f / (sqrtf(ab) + 1e-8f); }
    else { cs = beta / (sqrtf(1.f - ab) + 1e-8f); cd = 1.f / (sqrtf(1.f - beta) + 1e-8f); }
    ccg[qq] = make_float2(cs * cd, cd);
  }
}

// ---------------- LSTM layer 0 (MFMA; 16 batch/WG, 64 WGs x 512) ----------------
// in tile: [x(0..23) | h(24..151) | pad(152..159)], stride 160 halfs = 320 B.
__global__ __launch_bounds__(512, 2) void k_lstm0(const uint32_t* __restrict__ xh16,
                                                  const uint32_t* __restrict__ w0A,
                                                  const float* __restrict__ bs0,
                                                  __half* __restrict__ ys0) {
  __shared__ __align__(16) __half inb[2][16][160];
  const int tid = threadIdx.x;
  const int w = tid >> 6, l = tid & 63;
  const int n = l & 15, ql = l >> 4;
  const int ju = w * 16 + ql * 4;
  const int bbase = blockIdx.x * 16;

  uint4 Af[4][5];
#pragma unroll
  for (int T = 0; T < 4; T++)
#pragma unroll
    for (int f = 0; f < 5; f++)
      Af[T][f] = ((const uint4*)w0A)[((w * 4 + T) * 5 + f) * 64 + l];
  float bias[4][4];
#pragma unroll
  for (int T = 0; T < 4; T++)
#pragma unroll
    for (int r = 0; r < 4; r++) bias[T][r] = bs0[r * 128 + ju + T];

  for (int i = tid; i < 2560; i += 512) ((uint32_t*)inb)[i] = 0u;  // zero both bufs
  __syncthreads();
  if (tid < 192) {  // stage x_0 into buf 0
    int b = tid / 12, m = tid % 12;
    ((uint32_t*)&inb[0][b][0])[m] = xh16[(0 * 1024 + bbase + b) * 12 + m];
  }
  float cst[4] = {0.f, 0.f, 0.f, 0.f};
  __syncthreads();

  for (int t = 0; t < 96; t++) {
    const int cur = t & 1, nxt = cur ^ 1;
    uint32_t sx = 0;
    int sb = 0, sm = 0;
    if (t < 95 && tid < 192) {           // prefetch x_{t+1} under the MFMAs
      sb = tid / 12; sm = tid % 12;
      sx = xh16[((t + 1) * 1024 + bbase + sb) * 12 + sm];
    }
    v4f acc[4];
#pragma unroll
    for (int T = 0; T < 4; T++) acc[T] = (v4f){0.f, 0.f, 0.f, 0.f};
#pragma unroll
    for (int f = 0; f < 5; f++) {
      uint4 bu = *(const uint4*)&inb[cur][n][f * 32 + ql * 8];
      v8h Bv = __builtin_bit_cast(v8h, bu);
#pragma unroll
      for (int T = 0; T < 4; T++)
        acc[T] = __builtin_amdgcn_mfma_f32_16x16x32_f16(
            __builtin_bit_cast(v8h, Af[T][f]), Bv, acc[T], 0, 0, 0);
    }
    float hv[4];
#pragma unroll
    for (int T = 0; T < 4; T++) {
      float gi = acc[T][0] + bias[T][0];
      float gf = acc[T][1] + bias[T][1];
      float gg = acc[T][2] + bias[T][2];
      float go = acc[T][3] + bias[T][3];
      float c = sigm(gf) * cst[T] + sigm(gi) * tanh_f(gg);
      cst[T] = c;
      hv[T] = sigm(go) * tanh_f(c);
    }
    uint32_t h01 = pack2f(hv[0], hv[1]), h23 = pack2f(hv[2], hv[3]);
    *(uint2*)&inb[nxt][n][24 + ju] = make_uint2(h01, h23);
    *(uint2*)((__half*)ys0 + (size_t)(t * 1024 + bbase + n) * 128 + ju) = make_uint2(h01, h23);
    if (t < 95 && tid < 192) ((uint32_t*)&inb[nxt][sb][0])[sm] = sx;
    __syncthreads();
  }
}

// ---------------- LSTM layer 1 (MFMA; 16 batch/WG, 64 WGs x 512) ----------------
// in tile: [ys0_t(0..127) | h(128..255) | pad], stride 264 halfs = 528 B.
__global__ __launch_bounds__(512, 2) void k_lstm1(const uint32_t* __restrict__ ys0u,
                                                  const uint32_t* __restrict__ w1A,
                                                  const float* __restrict__ bs1,
                                                  float* __restrict__ enc) {
  __shared__ __align__(16) __half inb[2][16][264];
  const int tid = threadIdx.x;
  const int w = tid >> 6, l = tid & 63;
  const int n = l & 15, ql = l >> 4;
  const int ju = w * 16 + ql * 4;
  const int bbase = blockIdx.x * 16;
  const int sb = tid >> 5, sc = tid & 31;   // staging: batch, 8B-chunk

  uint4 Af[4][8];
#pragma unroll
  for (int T = 0; T < 4; T++)
#pragma unroll
    for (int f = 0; f < 8; f++)
      Af[T][f] = ((const uint4*)w1A)[((w * 4 + T) * 8 + f) * 64 + l];
  float bias[4][4];
#pragma unroll
  for (int T = 0; T < 4; T++)
#pragma unroll
    for (int r = 0; r < 4; r++) bias[T][r] = bs1[r * 128 + ju + T];

  for (int i = tid; i < 4224; i += 512) ((uint32_t*)inb)[i] = 0u;
  __syncthreads();
  {  // stage ys0[t=0] into buf 0
    uint2 v = ((const uint2*)ys0u)[(size_t)(0 * 1024 + bbase + sb) * 32 + sc];
    *(uint2*)&inb[0][sb][sc * 4] = v;
  }
  float cst[4] = {0.f, 0.f, 0.f, 0.f};
  __syncthreads();

  for (int t = 0; t < 96; t++) {
    const int cur = t & 1, nxt = cur ^ 1;
    uint2 sv = make_uint2(0u, 0u);
    if (t < 95)                          // prefetch ys0[t+1] under the MFMAs
      sv = ((const uint2*)ys0u)[(size_t)((t + 1) * 1024 + bbase + sb) * 32 + sc];
    v4f acc[4];
#pragma unroll
    for (int T = 0; T < 4; T++) acc[T] = (v4f){0.f, 0.f, 0.f, 0.f};
#pragma unroll
    for (int f = 0; f < 8; f++) {
      uint4 bu = *(const uint4*)&inb[cur][n][f * 32 + ql * 8];
      v8h Bv = __builtin_bit_cast(v8h, bu);
#pragma unroll
      for (int T = 0; T < 4; T++)
        acc[T] = __builtin_amdgcn_mfma_f32_16x16x32_f16(
            __builtin_bit_cast(v8h, Af[T][f]), Bv, acc[T], 0, 0, 0);
    }
    float hv[4];
#pragma unroll
    for (int T = 0; T < 4; T++) {
      float gi = acc[T][0] + bias[T][0];
      float gf = acc[T][1] + bias[T][1];
      float gg = acc[T][2] + bias[T][2];
      float go = acc[T][3] + bias[T][3];
      float c = sigm(gf) * cst[T] + sigm(gi) * tanh_f(gg);
      cst[T] = c;
      hv[T] = sigm(go) * tanh_f(c);
    }
    *(uint2*)&inb[nxt][n][128 + ju] = make_uint2(pack2f(hv[0], hv[1]), pack2f(hv[2], hv[3]));
    if (t < 95) *(uint2*)&inb[nxt][sb][sc * 4] = sv;
    if (t == 95)
      *(float4*)&enc[(size_t)(bbase + n) * 128 + ju] = make_float4(hv[0], hv[1], hv[2], hv[3]);
    __syncthreads();
  }
}

// ---------------- AR diffusion: 4-wave M-split, 16 batches/WG, 64 WGs ----
// W1 cols: [0:128) enc | [128:134) exo | [134:150) emb | 150 prev_y | 151 y |
//          [152:168) t_e | [168:184) h_e
// Wave w owns W2 tiles {2w, 2w+1} (8 MFMAs/wave, swapped operands: A=W2
// frag, B=h1 frag). tproj/cc prefetch from GLOBAL at step top (VMEM);
// partL[m][w*4+q] exchange; bt update AFTER the barrier in the ds_read
// latency shadow; y-update split pre/post barrier (ccG = (cs*cd, cd)).
__global__ __launch_bounds__(256, 1) void k_diff(
    const float* __restrict__ xfut, const float* __restrict__ y0,
    const int* __restrict__ tix, const float* __restrict__ noise,
    const float* __restrict__ temb, const float* __restrict__ W1,
    const float* __restrict__ b1, const float* __restrict__ b2,
    const float* __restrict__ W3, const float* __restrict__ b3,
    const uint32_t* __restrict__ w2p, const float* __restrict__ enc,
    const uint32_t* __restrict__ tpj, const uint32_t* __restrict__ hpj,
    const float2* __restrict__ ccG, float* __restrict__ out) {
  __shared__ uint32_t W1sL[128 * 65];                 // W1 cols 0..127 (stride 65)
  __shared__ uint32_t W1xL[128 * 29];                 // W1 cols 128..183 (stride 29)
  __shared__ uint32_t encPL[16 * 65];                 // enc fp16 pairs, 16 batches
  __shared__ uint32_t embPL[16 * 9];                  // emb fp16 pairs, 16 batches
  __shared__ uint32_t encdL[256 * 17];                // per-thread 16 pairs (+pad)
  __shared__ __align__(16) float partL[2][16][20];    // [buf][m][w*4+q] (+pad)

  const int tid = threadIdx.x;
  const int w = tid >> 6, l = tid & 63;
  const int m = l & 15, q = l >> 4;
  const int gbase = blockIdx.x * 16;                  // 16 batches per WG
  const uint4* tpj4 = (const uint4*)tpj;

  // ---- stage W1 / enc / emb ----
  for (int i = tid; i < 128 * 64; i += 256) {
    int r = i >> 6, c = i & 63;
    W1sL[r * 65 + c] = pack2f(W1[r * 184 + 2 * c], W1[r * 184 + 2 * c + 1]);
  }
  for (int i = tid; i < 128 * 28; i += 256) {
    int r = i / 28, c = i % 28;
    W1xL[r * 29 + c] = pack2f(W1[r * 184 + 128 + 2 * c], W1[r * 184 + 129 + 2 * c]);
  }
  for (int i = tid; i < 16 * 64; i += 256) {
    int bq = i >> 6, c = i & 63;
    encPL[bq * 65 + c] = pack2f(enc[(gbase + bq) * 128 + 2 * c],
                                enc[(gbase + bq) * 128 + 2 * c + 1]);
  }
  for (int i = tid; i < 16 * 8; i += 256) {
    int bq = i >> 3, c = i & 7;
    const float* er = temb + tix[gbase + bq] * 16;
    embPL[bq * 9 + c] = pack2f(er[2 * c], er[2 * c + 1]);
  }
  __syncthreads();

  // ---- per-lane constant part of base: b1 + W1_enc.enc + W1_emb.emb ----
  for (int pi = 0; pi < 16; pi++) {
    int k0 = (pi >> 2) * 32 + q * 8 + (pi & 3) * 2;
    half2_t a0 = {(_Float16)0.f, (_Float16)0.f};
    half2_t a1 = a0;
    const uint32_t* wr0 = &W1sL[k0 * 65];
    const uint32_t* wr1 = &W1sL[(k0 + 1) * 65];
    const uint32_t* ep = &encPL[m * 65];
#pragma unroll 8
    for (int c = 0; c < 64; c++) {
      half2_t e = __builtin_bit_cast(half2_t, ep[c]);
      a0 += __builtin_bit_cast(half2_t, wr0[c]) * e;
      a1 += __builtin_bit_cast(half2_t, wr1[c]) * e;
    }
#pragma unroll
    for (int c = 0; c < 8; c++) {
      half2_t e = __builtin_bit_cast(half2_t, embPL[m * 9 + c]);
      a0 += __builtin_bit_cast(half2_t, W1xL[k0 * 29 + 3 + c]) * e;       // cols 134..149
      a1 += __builtin_bit_cast(half2_t, W1xL[(k0 + 1) * 29 + 3 + c]) * e;
    }
    float e0 = b1[k0] + (float)a0.x + (float)a0.y;
    float e1 = b1[k0 + 1] + (float)a1.x + (float)a1.y;
    encdL[tid * 17 + pi] = pack2f(e0, e1);
  }

  // ---- per-wave resident: W2 tiles {2w, 2w+1}, packed b2/W3 for them ----
  uint4 Bf[2][4];
  {
    const uint4* w2u4 = (const uint4*)w2p;
#pragma unroll
    for (int j = 0; j < 2; j++)
#pragma unroll
      for (int f = 0; f < 4; f++)
        Bf[j][f] = w2u4[((2 * w + j) * 16 + m) * 16 + f * 4 + q];
  }
  uint32_t b2P[4], w3P[4];
#pragma unroll
  for (int j = 0; j < 2; j++) {
    int tt = 2 * w + j;
    b2P[2 * j]     = pack2f(b2[tt * 16 + q * 4 + 0], b2[tt * 16 + q * 4 + 1]);
    b2P[2 * j + 1] = pack2f(b2[tt * 16 + q * 4 + 2], b2[tt * 16 + q * 4 + 3]);
    w3P[2 * j]     = pack2f(W3[tt * 16 + q * 4 + 0], W3[tt * 16 + q * 4 + 1]);
    w3P[2 * j + 1] = pack2f(W3[tt * 16 + q * 4 + 2], W3[tt * 16 + q * 4 + 3]);
  }
  const float b3v = b3[0];
  const int pslot = w * 4 + q;                      // partL column

  uint32_t w1yP[16];
#pragma unroll
  for (int pi = 0; pi < 16; pi++) {
    int k0 = (pi >> 2) * 32 + q * 8 + (pi & 3) * 2;
    uint32_t ua = W1xL[k0 * 29 + 11];         // halfs: col150(lo), col151(hi)
    uint32_t ub = W1xL[(k0 + 1) * 29 + 11];
    w1yP[pi] = (ua >> 16) | (ub & 0xFFFF0000u);
  }

  float prev_y = y0[gbase + m];
  __syncthreads();

  float y = 0.f;
  float2 ccv = make_float2(0.f, 0.f);    // (cs*cd, cd) of current step
  uint32_t bph[16], bt[16];
  const v4f zf = (v4f){0.f, 0.f, 0.f, 0.f};

// one diffusion step at t_; bt holds bph+tproj[t_]; refreshes bt for t_-1.
// PB = partL buffer index (alternates 0/1 between consecutive calls).
#define DSTEP(t_, PB)                                                          \
  do {                                                                         \
    const int tn_ = ((t_) > 0) ? (t_) - 1 : 0;                                 \
    const uint4* tg_ = tpj4 + (size_t)(tn_ * 4 + q) * 4;   /* VMEM prefetch */ \
    uint4 t0 = tg_[0], t1 = tg_[1], t2 = tg_[2], t3 = tg_[3];                  \
    float2 cck_ = ccG[tn_];                                                    \
    const uint32_t yP = cvtpk(y);                                              \
    uint4 au[4];                                                               \
    _Pragma("unroll")                                                          \
    for (int f = 0; f < 4; f++) {                                              \
      au[f].x = pk_relufma(w1yP[4 * f + 0], yP, bt[4 * f + 0]);                \
      au[f].y = pk_relufma(w1yP[4 * f + 1], yP, bt[4 * f + 1]);                \
      au[f].z = pk_relufma(w1yP[4 * f + 2], yP, bt[4 * f + 2]);                \
      au[f].w = pk_relufma(w1yP[4 * f + 3], yP, bt[4 * f + 3]);                \
    }                                                                          \
    /* 8 MFMAs, 2 tiles x 2-deep split accumulators */                         \
    v4f a0 = __builtin_amdgcn_mfma_f32_16x16x32_f16(                           \
        __builtin_bit_cast(v8h, Bf[0][0]), __builtin_bit_cast(v8h, au[0]), zf, 0, 0, 0); \
    v4f b0 = __builtin_amdgcn_mfma_f32_16x16x32_f16(                           \
        __builtin_bit_cast(v8h, Bf[0][1]), __builtin_bit_cast(v8h, au[1]), zf, 0, 0, 0); \
    v4f a1 = __builtin_amdgcn_mfma_f32_16x16x32_f16(                           \
        __builtin_bit_cast(v8h, Bf[1][0]), __builtin_bit_cast(v8h, au[0]), zf, 0, 0, 0); \
    v4f b1x = __builtin_amdgcn_mfma_f32_16x16x32_f16(                          \
        __builtin_bit_cast(v8h, Bf[1][1]), __builtin_bit_cast(v8h, au[1]), zf, 0, 0, 0); \
    a0 = __builtin_amdgcn_mfma_f32_16x16x32_f16(                               \
        __builtin_bit_cast(v8h, Bf[0][2]), __builtin_bit_cast(v8h, au[2]), a0, 0, 0, 0); \
    b0 = __builtin_amdgcn_mfma_f32_16x16x32_f16(                               \
        __builtin_bit_cast(v8h, Bf[0][3]), __builtin_bit_cast(v8h, au[3]), b0, 0, 0, 0); \
    a1 = __builtin_amdgcn_mfma_f32_16x16x32_f16(                               \
        __builtin_bit_cast(v8h, Bf[1][2]), __builtin_bit_cast(v8h, au[2]), a1, 0, 0, 0); \
    b1x = __builtin_amdgcn_mfma_f32_16x16x32_f16(                              \
        __builtin_bit_cast(v8h, Bf[1][3]), __builtin_bit_cast(v8h, au[3]), b1x, 0, 0, 0); \
    v4f c0 = a0 + b0, c1 = a1 + b1x;                                           \
    /* packed epilogue: relu(c+b2) . w3, 2 tiles, 2 chains */                  \
    half2_t runA = {(_Float16)0.f, (_Float16)0.f};                             \
    half2_t runB = runA;                                                       \
    {                                                                          \
      uint32_t h01 = pk_max0(pk_add(cvtpk2(c0[0], c0[1]), b2P[0]));            \
      uint32_t h23 = pk_max0(pk_add(cvtpk2(c0[2], c0[3]), b2P[1]));            \
      runA = pk_fma2(h01, w3P[0], runA);                                       \
      runA = pk_fma2(h23, w3P[1], runA);                                       \
      uint32_t g01 = pk_max0(pk_add(cvtpk2(c1[0], c1[1]), b2P[2]));            \
      uint32_t g23 = pk_max0(pk_add(cvtpk2(c1[2], c1[3]), b2P[3]));            \
      runB = pk_fma2(g01, w3P[2], runB);                                       \
      runB = pk_fma2(g23, w3P[3], runB);                                       \
    }                                                                          \
    partL[PB][m][pslot] = ((float)runA.x + (float)runA.y) +                    \
                          ((float)runB.x + (float)runB.y);                     \
    const float pre_ = ccv.y * y - ccv.x * b3v;   /* cd*y - cs*cd*b3 */        \
    __syncthreads();                                                           \
    /* post-barrier: issue reads, bt update in the latency shadow */           \
    const v4f* pl_ = (const v4f*)&partL[PB][m][0];                             \
    v4f p0_ = pl_[0], p1_ = pl_[1], p2_ = pl_[2], p3_ = pl_[3];                \
    bt[0] = pk_add(bph[0], t0.x);   bt[1] = pk_add(bph[1], t0.y);              \
    bt[2] = pk_add(bph[2], t0.z);   bt[3] = pk_add(bph[3], t0.w);              \
    bt[4] = pk_add(bph[4], t1.x);   bt[5] = pk_add(bph[5], t1.y);              \
    bt[6] = pk_add(bph[6], t1.z);   bt[7] = pk_add(bph[7], t1.w);              \
    bt[8] = pk_add(bph[8], t2.x);   bt[9] = pk_add(bph[9], t2.y);              \
    bt[10] = pk_add(bph[10], t2.z); bt[11] = pk_add(bph[11], t2.w);            \
    bt[12] = pk_add(bph[12], t3.x); bt[13] = pk_add(bph[13], t3.y);            \
    bt[14] = pk_add(bph[14], t3.z); bt[15] = pk_add(bph[15], t3.w);            \
    v4f ps_ = (p0_ + p1_) + (p2_ + p3_);                                       \
    y = pre_ - ccv.x * ((ps_[0] + ps_[1]) + (ps_[2] + ps_[3]));                \
    ccv = cck_;                                                                \
  } while (0)

  for (int s = 0; s < 8; s++) {
    float yn = noise[s * 1024 + gbase + m];   // issued early, used after bph loop
    // base pairs for this AR step
    float xf[6];
#pragma unroll
    for (int i = 0; i < 6; i++) xf[i] = xfut[((gbase + m) * 8 + s) * 6 + i];
#pragma unroll
    for (int pi = 0; pi < 16; pi++) {
      int k0 = (pi >> 2) * 32 + q * 8 + (pi & 3) * 2;
      float2 ed = up2(encdL[tid * 17 + pi]);
      float e0 = ed.x, e1 = ed.y;
#pragma unroll
      for (int c = 0; c < 3; c++) {
        float2 w0v = up2(W1xL[k0 * 29 + c]);        // cols 128..133 (exo)
        float2 w1v = up2(W1xL[(k0 + 1) * 29 + c]);
        e0 += w0v.x * xf[2 * c] + w0v.y * xf[2 * c + 1];
        e1 += w1v.x * xf[2 * c] + w1v.y * xf[2 * c + 1];
      }
      e0 += up2(W1xL[k0 * 29 + 11]).x * prev_y;     // col 150
      e1 += up2(W1xL[(k0 + 1) * 29 + 11]).x * prev_y;
      float2 hh = up2(hpj[s * 64 + (k0 >> 1)]);
      e0 += hh.x;
      e1 += hh.y;
      bph[pi] = pack2f(e0, e1);
    }

    y = yn;
    {  // bt = bph + tproj[99]
      const uint4* tg = tpj4 + (size_t)(99 * 4 + q) * 4;
      uint4 t0 = tg[0], t1 = tg[1], t2 = tg[2], t3 = tg[3];
      bt[0] = pk_add(bph[0], t0.x);   bt[1] = pk_add(bph[1], t0.y);
      bt[2] = pk_add(bph[2], t0.z);   bt[3] = pk_add(bph[3], t0.w);
      bt[4] = pk_add(bph[4], t1.x);   bt[5] = pk_add(bph[5], t1.y);
      bt[6] = pk_add(bph[6], t1.z);   bt[7] = pk_add(bph[7], t1.w);
      bt[8] = pk_add(bph[8], t2.x);   bt[9] = pk_add(bph[9], t2.y);
      bt[10] = pk_add(bph[10], t2.z); bt[11] = pk_add(bph[11], t2.w);
      bt[12] = pk_add(bph[12], t3.x); bt[13] = pk_add(bph[13], t3.y);
      bt[14] = pk_add(bph[14], t3.z); bt[15] = pk_add(bph[15], t3.w);
    }
    ccv = ccG[99];

    for (int it = 0; it < 50; it++) {   // 100 steps, partL buffer ping-pong
      DSTEP(99 - 2 * it, 0);
      DSTEP(98 - 2 * it, 1);
    }

    if (w == 0 && l < 16) out[(gbase + l) * 8 + s] = y;
    prev_y = y;
  }
#undef DSTEP
}

// ---------------------------------------------------------------------------
extern "C" void kernel_launch(void* const* d_in, const int* in_sizes, int n_in,
                              void* d_out, int out_size, void* d_ws, size_t ws_size,
                              hipStream_t stream) {
  const float* x_hist    = (const float*)d_in[0];
  const float* x_future  = (const float*)d_in[1];
  const float* y0        = (const float*)d_in[2];
  const int*   turb_idx  = (const int*)d_in[3];
  const float* init_noise = (const float*)d_in[5];
  const float* turb_emb  = (const float*)d_in[6];
  const float* W_ih0     = (const float*)d_in[7];
  const float* W_hh0     = (const float*)d_in[8];
  const float* b_ih0     = (const float*)d_in[9];
  const float* b_hh0     = (const float*)d_in[10];
  const float* W_ih1     = (const float*)d_in[11];
  const float* W_hh1     = (const float*)d_in[12];
  const float* b_ih1     = (const float*)d_in[13];
  const float* b_hh1     = (const float*)d_in[14];
  const float* W1        = (const float*)d_in[15];
  const float* b1        = (const float*)d_in[16];
  const float* W2        = (const float*)d_in[17];
  const float* b2        = (const float*)d_in[18];
  const float* W3        = (const float*)d_in[19];
  const float* b3        = (const float*)d_in[20];

  char* ws = (char*)d_ws;
  uint32_t* xh16 = (uint32_t*)(ws + OFF_XH);
  uint32_t* w0p  = (uint32_t*)(ws + OFF_W0);
  float*    bs0  = (float*)(ws + OFF_BS0);
  uint32_t* w1p  = (uint32_t*)(ws + OFF_W1L);
  float*    bs1  = (float*)(ws + OFF_BS1);
  uint32_t* w2p  = (uint32_t*)(ws + OFF_W2P);
  float*    encf = (float*)(ws + OFF_ENC);
  __half*   ys0h = (__half*)(ws + OFF_YS0);
  uint32_t* tpjw = (uint32_t*)(ws + OFF_TPJ);
  uint32_t* hpjw = (uint32_t*)(ws + OFF_HPJ);
  float2*   ccw  = (float2*)(ws + OFF_CC);

  k_prep_xh<<<4608, 256, 0, stream>>>(x_hist, turb_idx, turb_emb, xh16);
  k_prep_w<<<480, 256, 0, stream>>>(W_ih0, W_hh0, b_ih0, b_hh0,
                                    W_ih1, W_hh1, b_ih1, b_hh1,
                                    W2, W1, w0p, w1p, w2p, bs0, bs1,
                                    tpjw, hpjw, ccw);
  k_lstm0<<<64, 512, 0, stream>>>(xh16, w0p, bs0, ys0h);
  k_lstm1<<<64, 512, 0, stream>>>((const uint32_t*)ys0h, w1p, bs1, encf);
  k_diff<<<64, 256, 0, stream>>>(x_future, y0, turb_idx, init_noise, turb_emb,
                                 W1, b1, b2, W3, b3, w2p, encf,
                                 tpjw, hpjw, ccw, (float*)d_out);
}